// Round 3
// baseline (523.165 us; speedup 1.0000x reference)
//
#include <hip/hip_runtime.h>
#include <hip/hip_bf16.h>

// CustomCLIP — M=196, b=32, d=512, n_cls=1000, N=4.
// inputs: image_features [6272][512], image_feature_pool [32][512],
//         text_features [4000][512], logit_scale scalar.
// Input/output dtype (fp32 vs bf16) detected at runtime from logit_scale's
// bit pattern (ln(1/0.07)=2.6593 is a known constant).
#define MB 6272
#define NC 4000
#define DD 512
#define NCLS 1000
#define NB 32000
#define NITER 16

typedef __attribute__((ext_vector_type(8))) short short8;
typedef __attribute__((ext_vector_type(4))) float f32x4;

__device__ __forceinline__ float bflo(unsigned u) { return __builtin_bit_cast(float, u << 16); }
__device__ __forceinline__ float bfhi(unsigned u) { return __builtin_bit_cast(float, u & 0xFFFF0000u); }
__device__ __forceinline__ float frcp(float x) { return __builtin_amdgcn_rcpf(x); }

__device__ __forceinline__ unsigned short f2bf(float x) {
  unsigned u = __builtin_bit_cast(unsigned, x);
  u += 0x7FFFu + ((u >> 16) & 1u);  // RNE; inputs are finite
  return (unsigned short)(u >> 16);
}

// dtype detector: logit_scale = 2.6593. bf16 mode -> first u16 decodes to ~2.66.
// fp32 mode -> first u16 is the fp32's low mantissa bits (decodes to ~2e-9).
__device__ __forceinline__ bool is_fp32_mode(const void* lsp) {
  const unsigned short u = *(const unsigned short*)lsp;
  const float v = __builtin_bit_cast(float, (unsigned)u << 16);
  return !(v > 2.55f && v < 2.77f);
}

__device__ __forceinline__ void load2(const void* base, size_t row, int t, bool f32,
                                      float& v0, float& v1) {
  if (f32) {
    const float* s = (const float*)base + row * DD;
    v0 = s[t]; v1 = s[t + 256];
  } else {
    const unsigned short* s = (const unsigned short*)base + row * DD;
    v0 = bflo(s[t]); v1 = bflo(s[t + 256]);
  }
}

// 8 consecutive elements at element-offset `off`, returned as 8 packed bf16.
__device__ __forceinline__ uint4 load8(const void* base, size_t off, bool f32) {
  if (!f32) return *reinterpret_cast<const uint4*>((const unsigned short*)base + off);
  const float4 a = *reinterpret_cast<const float4*>((const float*)base + off);
  const float4 b = *reinterpret_cast<const float4*>((const float*)base + off + 4);
  union { uint4 u; unsigned short h[8]; } r;
  r.h[0] = f2bf(a.x); r.h[1] = f2bf(a.y); r.h[2] = f2bf(a.z); r.h[3] = f2bf(a.w);
  r.h[4] = f2bf(b.x); r.h[5] = f2bf(b.y); r.h[6] = f2bf(b.z); r.h[7] = f2bf(b.w);
  return r.u;
}

// ---------------- prep: row rsqrt-norms + normalized pools (fp32 scratch) ----------------
// blocks: [0,6272) rnA, [6272,10272) rnB, [10272,10304) imgpool, [10304,11304) txtpool
__global__ void prep(const void* __restrict__ imgf, const void* __restrict__ imgp,
                     const void* __restrict__ txtf, const void* __restrict__ lsp,
                     float* __restrict__ rnA, float* __restrict__ rnB,
                     float* __restrict__ imgpool, float* __restrict__ txtpool) {
  const bool f32 = is_fp32_mode(lsp);
  const int row = blockIdx.x;
  const int t = threadIdx.x;
  __shared__ float red[256];
  float v0, v1;
  int mode;
  if (row < MB) {
    load2(imgf, row, t, f32, v0, v1); mode = 0;
  } else if (row < MB + NC) {
    load2(txtf, row - MB, t, f32, v0, v1); mode = 1;
  } else if (row < MB + NC + 32) {
    load2(imgp, row - MB - NC, t, f32, v0, v1); mode = 2;
  } else {
    const int cc = row - (MB + NC + 32);
    v0 = 0.f; v1 = 0.f;
#pragma unroll
    for (int n = 0; n < 4; ++n) {
      float a, b;
      load2(txtf, (size_t)n * NCLS + cc, t, f32, a, b);
      v0 += a; v1 += b;
    }
    v0 *= 0.25f; v1 *= 0.25f; mode = 3;
  }
  red[t] = v0 * v0 + v1 * v1;
  __syncthreads();
  for (int o = 128; o > 0; o >>= 1) {
    if (t < o) red[t] += red[t + o];
    __syncthreads();
  }
  const float rn = rsqrtf(red[0]);
  if (mode == 0) {
    if (t == 0) rnA[row] = rn;
  } else if (mode == 1) {
    if (t == 0) rnB[row - MB] = rn;
  } else if (mode == 2) {
    const int b = row - MB - NC;
    imgpool[(size_t)b * DD + t] = v0 * rn;
    imgpool[(size_t)b * DD + t + 256] = v1 * rn;
  } else {
    const int cc = row - (MB + NC + 32);
    txtpool[(size_t)cc * DD + t] = v0 * rn;
    txtpool[(size_t)cc * DD + t + 256] = v1 * rn;
  }
}

// ---------------- MFMA GEMM on raw features; K = exp(10*sim-10) -> bf16 ----------------
__global__ __launch_bounds__(256) void gemm_sim(const void* __restrict__ A,
                                                const void* __restrict__ Bm,
                                                const void* __restrict__ lsp,
                                                const float* __restrict__ rnA,
                                                const float* __restrict__ rnB,
                                                __hip_bfloat16* __restrict__ Kb) {
  const bool f32 = is_fp32_mode(lsp);
  __shared__ unsigned short As[128][32];
  __shared__ unsigned short Bs[128][32];
  const int t = threadIdx.x;
  const int row0 = blockIdx.x * 128;  // 6272 = 49*128 exact
  const int col0 = blockIdx.y * 128;  // 4000 -> 32 tiles, guarded
  const int lane = t & 63;
  const int w = t >> 6;
  const int wr = w >> 1, wc = w & 1;
  const int quad = lane >> 4, l16 = lane & 15;

  f32x4 acc[4][4];
#pragma unroll
  for (int i = 0; i < 4; ++i)
#pragma unroll
    for (int j = 0; j < 4; ++j) acc[i][j] = (f32x4)0.f;

  for (int k0 = 0; k0 < DD; k0 += 32) {
#pragma unroll
    for (int i = 0; i < 2; ++i) {
      const int idx = i * 256 + t;
      const int rr = idx >> 2;
      const int seg = idx & 3;
      *reinterpret_cast<uint4*>(&As[rr][seg * 8]) =
          load8(A, (size_t)(row0 + rr) * DD + k0 + seg * 8, f32);
      const int col = col0 + rr;
      uint4 bv = make_uint4(0u, 0u, 0u, 0u);
      if (col < NC) bv = load8(Bm, (size_t)col * DD + k0 + seg * 8, f32);
      *reinterpret_cast<uint4*>(&Bs[rr][seg * 8]) = bv;
    }
    __syncthreads();
    short8 af[4], bf[4];
#pragma unroll
    for (int rt = 0; rt < 4; ++rt)
      af[rt] = *reinterpret_cast<const short8*>(&As[wr * 64 + rt * 16 + l16][quad * 8]);
#pragma unroll
    for (int ct = 0; ct < 4; ++ct)
      bf[ct] = *reinterpret_cast<const short8*>(&Bs[wc * 64 + ct * 16 + l16][quad * 8]);
#pragma unroll
    for (int rt = 0; rt < 4; ++rt)
#pragma unroll
      for (int ct = 0; ct < 4; ++ct)
        acc[rt][ct] = __builtin_amdgcn_mfma_f32_16x16x32_bf16(af[rt], bf[ct], acc[rt][ct], 0, 0, 0);
    __syncthreads();
  }

  // epilogue: sim = raw_dot * rnA[row] * rnB[col]; K layout [b*1000+c][m*4+n]
#pragma unroll
  for (int rt = 0; rt < 4; ++rt) {
    const int rowbase = row0 + wr * 64 + rt * 16 + quad * 4;
    float ra[4];
#pragma unroll
    for (int reg = 0; reg < 4; ++reg) ra[reg] = rnA[rowbase + reg];
#pragma unroll
    for (int ct = 0; ct < 4; ++ct) {
      const int col = col0 + wc * 64 + ct * 16 + l16;
      if (col < NC) {
        const int n = col / NCLS;
        const int ccc = col - n * NCLS;
        const float rb = rnB[col];
#pragma unroll
        for (int reg = 0; reg < 4; ++reg) {
          const int rmb = rowbase + reg;
          const int m = rmb >> 5;
          const int b = rmb & 31;
          const float sim = acc[rt][ct][reg] * ra[reg] * rb;
          const float kv = __expf(10.f * sim - 10.f);
          ((unsigned short*)Kb)[(size_t)(b * NCLS + ccc) * 784 + m * 4 + n] = f2bf(kv);
        }
      }
    }
  }
}

// ---------------- sinkhorn: 4 lanes per row, c-state only, r recomputed ----------------
__global__ __launch_bounds__(256) void sinkhorn_k(const __hip_bfloat16* __restrict__ Kb_,
                                                  float* __restrict__ simop) {
  const unsigned short* Kb = (const unsigned short*)Kb_;
  const int tid = threadIdx.x;
  const int lane = tid & 63;
  const int wib = tid >> 6;
  const int rg = lane >> 2, q = lane & 3;
  const int row = (blockIdx.x * 4 + wib) * 16 + rg;
  const unsigned short* Kr = Kb + (size_t)row * 784 + q * 196;

  float c0 = 1.f, c1 = 1.f, c2 = 1.f, c3 = 1.f;
  for (int it = 0; it < NITER; ++it) {
    float S0 = 0.f, S1 = 0.f, S2 = 0.f, S3 = 0.f;
#pragma unroll 7
    for (int i = 0; i < 49; ++i) {
      const uint2 u = *reinterpret_cast<const uint2*>(Kr + i * 4);
      const float k0 = bflo(u.x), k1 = bfhi(u.x), k2 = bflo(u.y), k3 = bfhi(u.y);
      const float den = k0 * c0 + k1 * c1 + k2 * c2 + k3 * c3;
      const float rv = (1.0f / 196.0f) * frcp(den);
      S0 += k0 * rv; S1 += k1 * rv; S2 += k2 * rv; S3 += k3 * rv;
    }
    S0 += __shfl_xor(S0, 1); S0 += __shfl_xor(S0, 2);
    S1 += __shfl_xor(S1, 1); S1 += __shfl_xor(S1, 2);
    S2 += __shfl_xor(S2, 1); S2 += __shfl_xor(S2, 2);
    S3 += __shfl_xor(S3, 1); S3 += __shfl_xor(S3, 2);
    c0 = 0.25f * frcp(S0); c1 = 0.25f * frcp(S1);
    c2 = 0.25f * frcp(S2); c3 = 0.25f * frcp(S3);
  }
  float acc = 0.f;
#pragma unroll 7
  for (int i = 0; i < 49; ++i) {
    const uint2 u = *reinterpret_cast<const uint2*>(Kr + i * 4);
    const float k0 = bflo(u.x), k1 = bfhi(u.x), k2 = bflo(u.y), k3 = bfhi(u.y);
    const float den = k0 * c0 + k1 * c1 + k2 * c2 + k3 * c3;
    const float rv = (1.0f / 196.0f) * frcp(den);
    float s;
    s  = c0 * k0 * (1.0f + 0.1f * __logf(k0));
    s += c1 * k1 * (1.0f + 0.1f * __logf(k1));
    s += c2 * k2 * (1.0f + 0.1f * __logf(k2));
    s += c3 * k3 * (1.0f + 0.1f * __logf(k3));
    acc += rv * s;
  }
  acc += __shfl_xor(acc, 1); acc += __shfl_xor(acc, 2);
  if (q == 0) simop[row] = acc;
}

// ---------------- final: out = 0.5*ls*(sim_op + img_pool . txt_pool) ----------------
__global__ void final_kern(const float* __restrict__ simop,
                           const float* __restrict__ imgpool,
                           const float* __restrict__ txtpool,
                           const void* __restrict__ lsp,
                           void* __restrict__ out) {
  const bool f32 = is_fp32_mode(lsp);
  const int w = blockIdx.x * 4 + (threadIdx.x >> 6);  // 0..31999
  const int lane = threadIdx.x & 63;
  const int b = w / NCLS;
  const int cc = w - b * NCLS;
  const float* ip = imgpool + (size_t)b * DD;
  const float* tp = txtpool + (size_t)cc * DD;
  float s = 0.f;
#pragma unroll
  for (int j = 0; j < 8; ++j) {
    const int d = j * 64 + lane;
    s += ip[d] * tp[d];
  }
#pragma unroll
  for (int off = 1; off < 64; off <<= 1) s += __shfl_xor(s, off);
  if (lane == 0) {
    const float lsv = f32 ? *(const float*)lsp
                          : bflo(*(const unsigned short*)lsp);
    const float val = 0.5f * __expf(lsv) * (simop[w] + s);
    if (f32) ((float*)out)[w] = val;
    else ((unsigned short*)out)[w] = f2bf(val);
  }
}

extern "C" void kernel_launch(void* const* d_in, const int* in_sizes, int n_in,
                              void* d_out, int out_size, void* d_ws, size_t ws_size,
                              hipStream_t stream) {
  const void* imgf = d_in[0];
  const void* imgp = d_in[1];
  const void* txtf = d_in[2];
  const void* lsp  = d_in[3];

  const size_t need = (size_t)NB * 784 * 2 + MB * 4 + NC * 4 + 32 * DD * 4 +
                      NCLS * DD * 4 + NB * 4;
  const bool ok = (n_in == 4) && in_sizes[0] == MB * DD && in_sizes[1] == 32 * DD &&
                  in_sizes[2] == NC * DD && in_sizes[3] == 1 && out_size == NB &&
                  ws_size >= need;
  if (!ok) return;  // out stays harness-zeroed -> absmax = max|ref| diagnostic

  char* w = (char*)d_ws;
  __hip_bfloat16* Kb = (__hip_bfloat16*)w; w += (size_t)NB * 784 * 2;  // 50,176,000
  float* rnA = (float*)w;                  w += MB * 4;
  float* rnB = (float*)w;                  w += NC * 4;
  float* imgpool = (float*)w;              w += 32 * DD * 4;
  float* txtpool = (float*)w;              w += NCLS * DD * 4;
  float* simop = (float*)w;                w += NB * 4;

  prep<<<dim3(MB + NC + 32 + NCLS), dim3(256), 0, stream>>>(imgf, imgp, txtf, lsp,
                                                            rnA, rnB, imgpool, txtpool);
  gemm_sim<<<dim3(49, 32), dim3(256), 0, stream>>>(imgf, txtf, lsp, rnA, rnB, Kb);
  sinkhorn_k<<<dim3(500), dim3(256), 0, stream>>>(Kb, simop);
  final_kern<<<dim3(NB / 4), dim3(256), 0, stream>>>(simop, imgpool, txtpool, lsp, d_out);
}

// Round 4
// 256.107 us; speedup vs baseline: 2.0428x; 2.0428x over previous
//
#include <hip/hip_runtime.h>
#include <hip/hip_bf16.h>

// CustomCLIP — M=196, b=32, d=512, n_cls=1000, N=4.
// fp32/bf16 input mode detected from logit_scale bit pattern.
// K layout: [m][p*4+n], p = b*1000+c  (GEMM-coalesced AND sinkhorn-coalesced;
// GEMM consumes B row-permuted j = c*4+n so epilogue cols are j-contiguous).
#define MB 6272
#define NC 4000
#define DD 512
#define NCLS 1000
#define NB 32000
#define NITER 8   // ref early-exits ~iter 2-4; fixed point reached well before 8

typedef __attribute__((ext_vector_type(8))) short short8;
typedef __attribute__((ext_vector_type(4))) float f32x4;

__device__ __forceinline__ float bflo(unsigned u) { return __builtin_bit_cast(float, u << 16); }
__device__ __forceinline__ float bfhi(unsigned u) { return __builtin_bit_cast(float, u & 0xFFFF0000u); }
__device__ __forceinline__ float frcp(float x) { return __builtin_amdgcn_rcpf(x); }

__device__ __forceinline__ unsigned short f2bf(float x) {
  unsigned u = __builtin_bit_cast(unsigned, x);
  u += 0x7FFFu + ((u >> 16) & 1u);  // RNE; finite inputs
  return (unsigned short)(u >> 16);
}

__device__ __forceinline__ bool is_fp32_mode(const void* lsp) {
  const unsigned short u = *(const unsigned short*)lsp;
  const float v = __builtin_bit_cast(float, (unsigned)u << 16);
  return !(v > 2.55f && v < 2.77f);  // ln(1/0.07)=2.659 decodes here iff bf16 mode
}

__device__ __forceinline__ void load2(const void* base, size_t row, int t, bool f32,
                                      float& v0, float& v1) {
  if (f32) {
    const float* s = (const float*)base + row * DD;
    v0 = s[t]; v1 = s[t + 256];
  } else {
    const unsigned short* s = (const unsigned short*)base + row * DD;
    v0 = bflo(s[t]); v1 = bflo(s[t + 256]);
  }
}

__device__ __forceinline__ uint4 load8(const void* base, size_t off, bool f32) {
  if (!f32) return *reinterpret_cast<const uint4*>((const unsigned short*)base + off);
  const float4 a = *reinterpret_cast<const float4*>((const float*)base + off);
  const float4 b = *reinterpret_cast<const float4*>((const float*)base + off + 4);
  union { uint4 u; unsigned short h[8]; } r;
  r.h[0] = f2bf(a.x); r.h[1] = f2bf(a.y); r.h[2] = f2bf(a.z); r.h[3] = f2bf(a.w);
  r.h[4] = f2bf(b.x); r.h[5] = f2bf(b.y); r.h[6] = f2bf(b.z); r.h[7] = f2bf(b.w);
  return r.u;
}

// ---------------- prep: row rsqrt-norms (rnB permuted j=c*4+n) + fp32 pools ----------------
__global__ void prep(const void* __restrict__ imgf, const void* __restrict__ imgp,
                     const void* __restrict__ txtf, const void* __restrict__ lsp,
                     float* __restrict__ rnA, float* __restrict__ rnB,
                     float* __restrict__ imgpool, float* __restrict__ txtpool) {
  const bool f32 = is_fp32_mode(lsp);
  const int row = blockIdx.x;
  const int t = threadIdx.x;
  __shared__ float red[256];
  float v0, v1;
  int mode;
  if (row < MB) {
    load2(imgf, row, t, f32, v0, v1); mode = 0;
  } else if (row < MB + NC) {
    const int j = row - MB;                      // dest index c*4+n
    const int src = (j & 3) * NCLS + (j >> 2);   // text row n*1000+c
    load2(txtf, src, t, f32, v0, v1); mode = 1;
  } else if (row < MB + NC + 32) {
    load2(imgp, row - MB - NC, t, f32, v0, v1); mode = 2;
  } else {
    const int cc = row - (MB + NC + 32);
    v0 = 0.f; v1 = 0.f;
#pragma unroll
    for (int n = 0; n < 4; ++n) {
      float a, b;
      load2(txtf, (size_t)n * NCLS + cc, t, f32, a, b);
      v0 += a; v1 += b;
    }
    v0 *= 0.25f; v1 *= 0.25f; mode = 3;
  }
  red[t] = v0 * v0 + v1 * v1;
  __syncthreads();
  for (int o = 128; o > 0; o >>= 1) {
    if (t < o) red[t] += red[t + o];
    __syncthreads();
  }
  const float rn = rsqrtf(red[0]);
  if (mode == 0) {
    if (t == 0) rnA[row] = rn;
  } else if (mode == 1) {
    if (t == 0) rnB[row - MB] = rn;
  } else if (mode == 2) {
    const int b = row - MB - NC;
    imgpool[(size_t)b * DD + t] = v0 * rn;
    imgpool[(size_t)b * DD + t + 256] = v1 * rn;
  } else {
    const int cc = row - (MB + NC + 32);
    txtpool[(size_t)cc * DD + t] = v0 * rn;
    txtpool[(size_t)cc * DD + t + 256] = v1 * rn;
  }
}

// ---------------- MFMA GEMM; K = exp(10*sim-10) -> bf16, coalesced [m][p*4+n] ----------------
__global__ __launch_bounds__(256) void gemm_sim(const void* __restrict__ A,
                                                const void* __restrict__ Bm,
                                                const void* __restrict__ lsp,
                                                const float* __restrict__ rnA,
                                                const float* __restrict__ rnB,
                                                unsigned short* __restrict__ Km) {
  const bool f32 = is_fp32_mode(lsp);
  __shared__ unsigned short As[128][32];
  __shared__ unsigned short Bs[128][32];
  const int t = threadIdx.x;
  const int row0 = blockIdx.x * 128;  // 6272 = 49*128
  const int col0 = blockIdx.y * 128;  // j-cols, 4000 -> 32 tiles, guarded
  const int lane = t & 63;
  const int w = t >> 6;
  const int wr = w >> 1, wc = w & 1;
  const int quad = lane >> 4, l16 = lane & 15;

  f32x4 acc[4][4];
#pragma unroll
  for (int i = 0; i < 4; ++i)
#pragma unroll
    for (int j = 0; j < 4; ++j) acc[i][j] = (f32x4)0.f;

  for (int k0 = 0; k0 < DD; k0 += 32) {
#pragma unroll
    for (int i = 0; i < 2; ++i) {
      const int idx = i * 256 + t;
      const int rr = idx >> 2;
      const int seg = idx & 3;
      *reinterpret_cast<uint4*>(&As[rr][seg * 8]) =
          load8(A, (size_t)(row0 + rr) * DD + k0 + seg * 8, f32);
      const int j = col0 + rr;  // dest col = c*4+n -> source text row n*1000+c
      uint4 bv = make_uint4(0u, 0u, 0u, 0u);
      if (j < NC)
        bv = load8(Bm, (size_t)((j & 3) * NCLS + (j >> 2)) * DD + k0 + seg * 8, f32);
      *reinterpret_cast<uint4*>(&Bs[rr][seg * 8]) = bv;
    }
    __syncthreads();
    short8 af[4], bf[4];
#pragma unroll
    for (int rt = 0; rt < 4; ++rt)
      af[rt] = *reinterpret_cast<const short8*>(&As[wr * 64 + rt * 16 + l16][quad * 8]);
#pragma unroll
    for (int ct = 0; ct < 4; ++ct)
      bf[ct] = *reinterpret_cast<const short8*>(&Bs[wc * 64 + ct * 16 + l16][quad * 8]);
#pragma unroll
    for (int rt = 0; rt < 4; ++rt)
#pragma unroll
      for (int ct = 0; ct < 4; ++ct)
        acc[rt][ct] = __builtin_amdgcn_mfma_f32_16x16x32_bf16(af[rt], bf[ct], acc[rt][ct], 0, 0, 0);
    __syncthreads();
  }

  // epilogue: sim = dot * rnA * rnB; Km[m*128000 + b*4000 + j] — j-contiguous per lane row
#pragma unroll
  for (int rt = 0; rt < 4; ++rt) {
    const int rowbase = row0 + wr * 64 + rt * 16 + quad * 4;
    float ra[4];
#pragma unroll
    for (int reg = 0; reg < 4; ++reg) ra[reg] = rnA[rowbase + reg];
#pragma unroll
    for (int ct = 0; ct < 4; ++ct) {
      const int j = col0 + wc * 64 + ct * 16 + l16;
      if (j < NC) {
        const float rb = rnB[j];
#pragma unroll
        for (int reg = 0; reg < 4; ++reg) {
          const int rmb = rowbase + reg;
          const int m = rmb >> 5;
          const int b = rmb & 31;
          const float sim = acc[rt][ct][reg] * ra[reg] * rb;
          Km[(size_t)m * 128000 + b * 4000 + j] = f2bf(__expf(10.f * sim - 10.f));
        }
      }
    }
  }
}

// ---------------- sinkhorn: lane owns problem p; 4 waves split m; LDS reduce ----------------
__global__ __launch_bounds__(256) void sinkhorn_k(const unsigned short* __restrict__ Km,
                                                  float* __restrict__ simop) {
  const int lane = threadIdx.x & 63;
  const int w = threadIdx.x >> 6;
  const int p = blockIdx.x * 64 + lane;
  const unsigned short* Kw = Km + (size_t)(w * 49) * 128000 + (size_t)p * 4;

  __shared__ f32x4 red[64][4];  // [lane][wave]

  float c0 = 1.f, c1 = 1.f, c2 = 1.f, c3 = 1.f;
  for (int it = 0; it < NITER - 1; ++it) {
    float S0 = 0.f, S1 = 0.f, S2 = 0.f, S3 = 0.f;
#pragma unroll 7
    for (int i = 0; i < 49; ++i) {
      const uint2 u = *reinterpret_cast<const uint2*>(Kw + (size_t)i * 128000);
      const float k0 = bflo(u.x), k1 = bfhi(u.x), k2 = bflo(u.y), k3 = bfhi(u.y);
      const float den = (k0 * c0 + k1 * c1) + (k2 * c2 + k3 * c3);
      const float rv = (1.0f / 196.0f) * frcp(den);
      S0 += k0 * rv; S1 += k1 * rv; S2 += k2 * rv; S3 += k3 * rv;
    }
    f32x4 s; s[0] = S0; s[1] = S1; s[2] = S2; s[3] = S3;
    red[lane][w] = s;
    __syncthreads();
    const f32x4 tot = (red[lane][0] + red[lane][1]) + (red[lane][2] + red[lane][3]);
    c0 = 0.25f * frcp(tot[0]); c1 = 0.25f * frcp(tot[1]);
    c2 = 0.25f * frcp(tot[2]); c3 = 0.25f * frcp(tot[3]);
    __syncthreads();
  }

  // last iteration fused with sim_op: W_n = sum_m r_m K sim (indep of final c)
  float S0 = 0.f, S1 = 0.f, S2 = 0.f, S3 = 0.f;
  float W0 = 0.f, W1 = 0.f, W2 = 0.f, W3 = 0.f;
#pragma unroll 7
  for (int i = 0; i < 49; ++i) {
    const uint2 u = *reinterpret_cast<const uint2*>(Kw + (size_t)i * 128000);
    const float k0 = bflo(u.x), k1 = bfhi(u.x), k2 = bflo(u.y), k3 = bfhi(u.y);
    const float den = (k0 * c0 + k1 * c1) + (k2 * c2 + k3 * c3);
    const float rv = (1.0f / 196.0f) * frcp(den);
    S0 += k0 * rv; S1 += k1 * rv; S2 += k2 * rv; S3 += k3 * rv;
    W0 += rv * k0 * (1.0f + 0.1f * __logf(k0));
    W1 += rv * k1 * (1.0f + 0.1f * __logf(k1));
    W2 += rv * k2 * (1.0f + 0.1f * __logf(k2));
    W3 += rv * k3 * (1.0f + 0.1f * __logf(k3));
  }
  f32x4 s; s[0] = S0; s[1] = S1; s[2] = S2; s[3] = S3;
  red[lane][w] = s;
  __syncthreads();
  const f32x4 st = (red[lane][0] + red[lane][1]) + (red[lane][2] + red[lane][3]);
  __syncthreads();
  f32x4 wv; wv[0] = W0; wv[1] = W1; wv[2] = W2; wv[3] = W3;
  red[lane][w] = wv;
  __syncthreads();
  const f32x4 wt = (red[lane][0] + red[lane][1]) + (red[lane][2] + red[lane][3]);
  if (w == 0) {
    const float cf0 = 0.25f * frcp(st[0]), cf1 = 0.25f * frcp(st[1]);
    const float cf2 = 0.25f * frcp(st[2]), cf3 = 0.25f * frcp(st[3]);
    simop[p] = (cf0 * wt[0] + cf1 * wt[1]) + (cf2 * wt[2] + cf3 * wt[3]);
  }
}

// ---------------- final: out = 0.5*ls*(sim_op + img_pool . txt_pool) ----------------
__global__ void final_kern(const float* __restrict__ simop,
                           const float* __restrict__ imgpool,
                           const float* __restrict__ txtpool,
                           const void* __restrict__ lsp,
                           void* __restrict__ out) {
  const bool f32 = is_fp32_mode(lsp);
  const int w = blockIdx.x * 4 + (threadIdx.x >> 6);  // 0..31999
  const int lane = threadIdx.x & 63;
  const int b = w / NCLS;
  const int cc = w - b * NCLS;
  const float* ip = imgpool + (size_t)b * DD;
  const float* tp = txtpool + (size_t)cc * DD;
  float s = 0.f;
#pragma unroll
  for (int j = 0; j < 8; ++j) {
    const int d = j * 64 + lane;
    s += ip[d] * tp[d];
  }
#pragma unroll
  for (int off = 1; off < 64; off <<= 1) s += __shfl_xor(s, off);
  if (lane == 0) {
    const float lsv = f32 ? *(const float*)lsp : bflo(*(const unsigned short*)lsp);
    const float val = 0.5f * __expf(lsv) * (simop[w] + s);
    if (f32) ((float*)out)[w] = val;
    else ((unsigned short*)out)[w] = f2bf(val);
  }
}

extern "C" void kernel_launch(void* const* d_in, const int* in_sizes, int n_in,
                              void* d_out, int out_size, void* d_ws, size_t ws_size,
                              hipStream_t stream) {
  const void* imgf = d_in[0];
  const void* imgp = d_in[1];
  const void* txtf = d_in[2];
  const void* lsp  = d_in[3];

  const size_t need = (size_t)NB * 784 * 2 + MB * 4 + NC * 4 + 32 * DD * 4 +
                      NCLS * DD * 4 + NB * 4;  // 52,458,624 (proven OK round 3)
  const bool ok = (n_in == 4) && in_sizes[0] == MB * DD && in_sizes[1] == 32 * DD &&
                  in_sizes[2] == NC * DD && in_sizes[3] == 1 && out_size == NB &&
                  ws_size >= need;
  if (!ok) return;

  char* w = (char*)d_ws;
  unsigned short* Km = (unsigned short*)w; w += (size_t)NB * 784 * 2;  // 50,176,000
  float* rnA = (float*)w;                  w += MB * 4;
  float* rnB = (float*)w;                  w += NC * 4;
  float* imgpool = (float*)w;              w += 32 * DD * 4;
  float* txtpool = (float*)w;              w += NCLS * DD * 4;
  float* simop = (float*)w;                w += NB * 4;

  prep<<<dim3(MB + NC + 32 + NCLS), dim3(256), 0, stream>>>(imgf, imgp, txtf, lsp,
                                                            rnA, rnB, imgpool, txtpool);
  gemm_sim<<<dim3(49, 32), dim3(256), 0, stream>>>(imgf, txtf, lsp, rnA, rnB, Km);
  sinkhorn_k<<<dim3(500), dim3(256), 0, stream>>>(Km, simop);
  final_kern<<<dim3(NB / 4), dim3(256), 0, stream>>>(simop, imgpool, txtpool, lsp, d_out);
}